// Round 11
// baseline (313.801 us; speedup 1.0000x reference)
//
#include <hip/hip_runtime.h>
#include <math.h>

typedef __bf16 bf16x8 __attribute__((ext_vector_type(8)));
typedef float  f32x4  __attribute__((ext_vector_type(4)));
typedef float  f32x2  __attribute__((ext_vector_type(2)));
typedef unsigned short ushort_t;
typedef unsigned short ushort8 __attribute__((ext_vector_type(8)));

// Problem constants (fixed by the reference).
constexpr int Nn = 50000;   // nodes
constexpr int Ee = 800000;  // edges
constexpr int Dd = 128;     // feature dim
constexpr int Gg = 64;      // graphs
constexpr float SCALE = 0.08838834764831845f; // 1/sqrt(128)
constexpr float QS    = 16.0f;                 // int8 quant scale for q,k
constexpr float ISC   = SCALE / (QS * QS);     // int-dot -> alpha

constexpr int CPAD = 16;    // counts stride: 1 counter per 64B line (R7: confirmed
                            // memory-side atomics serialize per granule)

__device__ inline ushort_t f2bf(float f) {
    unsigned u = __float_as_uint(f);
    unsigned r = (u + 0x7FFF + ((u >> 16) & 1)) >> 16;   // RNE truncate to bf16
    return (ushort_t)r;
}
__device__ inline float bf2f(ushort_t b) { return __uint_as_float(((unsigned)b) << 16); }

__device__ inline char q_i8(float f) {
    int v = (int)rintf(f * QS);
    v = max(-127, min(127, v));
    return (char)v;
}

// bijective XCD-grouping swizzle (m204 form): blockIdx b round-robins XCDs
// (xcd = b%8); remap so each XCD owns a CONTIGUOUS work-id range -> the 4
// variant-blocks of a row-tile (adjacent work ids) land on the SAME XCD L2.
// R8 counter evidence: gemm0 FETCH 56 -> 19.4 MB. KEEP.
__device__ inline int xcd_group(int b, int n) {
    int q = n >> 3, r = n & 7;
    int xcd = b & 7, idx = b >> 3;
    int base = (xcd < r) ? xcd * (q + 1) : r * (q + 1) + (xcd - r) * q;
    return base + idx;
}

// ---------------- fused prep: hist(+rank) + graph bounds + convw + convx ----

constexpr int EB8 = (Ee + 2047) / 2048; // 391 hist blocks (8 edges/thread)
constexpr int NBD = (Nn + 255) / 256;   // 196 bound blocks
constexpr int CWB = 64;                 // convw blocks
constexpr int N8  = Nn * Dd / 8;        // 800000 8-float chunks
constexpr int CXB = N8 / 256;           // 3125 convx blocks

__global__ __launch_bounds__(256) void prep_kernel(
    const int* __restrict__ dst, int* __restrict__ counts, int* __restrict__ rank,
    const int* __restrict__ batch, int* __restrict__ startg, int* __restrict__ endg,
    const float* w0, const float* w1, const float* w2, const float* w3,
    const float* w4, const float* w5, const float* w6, const float* w7,
    ushort_t* __restrict__ Wfh, ushort_t* __restrict__ Wfl,
    const float* __restrict__ x, ushort_t* __restrict__ Xh, ushort_t* __restrict__ Xl) {
    int b = blockIdx.x;
    if (b < EB8) {                                  // ---- histogram + rank, 8/thr
        int e0 = (b * 256 + threadIdx.x) * 8;
        if (e0 >= Ee) return;                       // Ee % 8 == 0 -> full groups
        int4 d0 = *(const int4*)(dst + e0);
        int4 d1 = *(const int4*)(dst + e0 + 4);
        int r0 = atomicAdd(&counts[d0.x * CPAD], 1);
        int r1 = atomicAdd(&counts[d0.y * CPAD], 1);
        int r2 = atomicAdd(&counts[d0.z * CPAD], 1);
        int r3 = atomicAdd(&counts[d0.w * CPAD], 1);
        int r4 = atomicAdd(&counts[d1.x * CPAD], 1);
        int r5 = atomicAdd(&counts[d1.y * CPAD], 1);
        int r6 = atomicAdd(&counts[d1.z * CPAD], 1);
        int r7 = atomicAdd(&counts[d1.w * CPAD], 1);
        *(int4*)(rank + e0)     = (int4){r0, r1, r2, r3};
        *(int4*)(rank + e0 + 4) = (int4){r4, r5, r6, r7};
    } else if (b < EB8 + NBD) {                     // ---- graph bounds
        int n = (b - EB8) * 256 + threadIdx.x;
        if (n >= Nn) return;
        int g = batch[n];
        if (n == Nn - 1 || batch[n + 1] != g) endg[g] = n + 1;
        if (n == 0 || batch[n - 1] != g) startg[g] = n;
    } else if (b < EB8 + NBD + CWB) {               // ---- fragment-order weights
        const float* ws[8] = {w0, w1, w2, w3, w4, w5, w6, w7};
        int b2 = b - (EB8 + NBD);
        int m = b2 >> 3;
        int tt = (b2 & 7) * 256 + threadIdx.x;      // 0..2047 fragment slots
        int lane = tt & 63;
        int ln = lane & 15, quad = lane >> 4;
        int n = (tt >> 9) * 32 + ((tt >> 8) & 1) * 16 + ln;
        int k0 = ((tt >> 6) & 3) * 32 + quad * 8;
        const float* srcp = ws[m] + n * 128 + k0;
        float4 a = *(const float4*)(srcp);
        float4 bb = *(const float4*)(srcp + 4);
        float e[8] = {a.x, a.y, a.z, a.w, bb.x, bb.y, bb.z, bb.w};
        ushort8 h, l;
#pragma unroll
        for (int j = 0; j < 8; ++j) {
            h[j] = f2bf(e[j]);
            l[j] = f2bf(e[j] - bf2f(h[j]));
        }
        size_t o = (size_t)m * 16384 + (size_t)tt * 8;
        *(ushort8*)(Wfh + o) = h;
        *(ushort8*)(Wfl + o) = l;
    } else {                                        // ---- split-bf16 convx (8 f/thr)
        int i = (b - (EB8 + NBD + CWB)) * 256 + threadIdx.x;
        if (i >= N8) return;
        float4 xa = ((const float4*)x)[i * 2];
        float4 xb = ((const float4*)x)[i * 2 + 1];
        float e[8] = {xa.x, xa.y, xa.z, xa.w, xb.x, xb.y, xb.z, xb.w};
        ushort8 h, l;
#pragma unroll
        for (int j = 0; j < 8; ++j) {
            h[j] = f2bf(e[j]);
            l[j] = f2bf(e[j] - bf2f(h[j]));
        }
        ((ushort8*)Xh)[i] = h;
        ((ushort8*)Xl)[i] = l;
    }
}

// ---------------- scans (CSR offsets) ----------------
// scan3 folded into consumers (offsets[i] + blockSums[i>>8]).

__global__ __launch_bounds__(256) void scan1_kernel(const int* __restrict__ counts,
                                                    int* __restrict__ offsets,
                                                    int* __restrict__ blockSums) {
    __shared__ int sh[256];
    int i = blockIdx.x * 256 + threadIdx.x;
    int v = (i < Nn) ? counts[i * CPAD] : 0;
    sh[threadIdx.x] = v;
    __syncthreads();
    for (int off = 1; off < 256; off <<= 1) {
        int t = (threadIdx.x >= off) ? sh[threadIdx.x - off] : 0;
        __syncthreads();
        sh[threadIdx.x] += t;
        __syncthreads();
    }
    if (i < Nn) offsets[i] = sh[threadIdx.x] - v;   // exclusive within block
    if (threadIdx.x == 255) blockSums[blockIdx.x] = sh[255];
}

__global__ __launch_bounds__(256) void scan2_kernel(int* __restrict__ blockSums, int nb) {
    __shared__ int sh[256];
    int t = threadIdx.x;
    int v = (t < nb) ? blockSums[t] : 0;
    sh[t] = v;
    __syncthreads();
    for (int off = 1; off < 256; off <<= 1) {
        int u = (t >= off) ? sh[t - off] : 0;
        __syncthreads();
        sh[t] += u;
        __syncthreads();
    }
    if (t < nb) blockSums[t] = sh[t] - v;           // exclusive across blocks
}

// ---------------- MFMA split-bf16 GEMM body: Y = X @ W^T + b ----------------
// v9: FULL-TILE STAGE -- all 128 rows staged upfront (16 loads/thread issued
// back-to-back, 8KB/wave in flight vs 2KB), then ONE barrier and 8 rt of
// uninterrupted ds_read+MFMA. Barriers per block: 8 -> 2. LDS 69.6KB dynamic
// (2 blocks/CU; R1/R3 showed residency 4..9 blocks was perf-neutral, so we
// trade residency for stage burst depth). Epilogue = R9 byte-store form
// (R10's wide-store swap was falsified: WRITE_SIZE unchanged).
// q,k out INT8 (scale 16); v out FP8-e4m3; s out bf16.

constexpr int XS = 136;   // LDS row stride in shorts (pad -> bank rotate)
constexpr int NT = (Nn + 127) / 128;    // 391 row tiles
constexpr unsigned GEMM_LDS = 2u * 128 * XS * sizeof(ushort_t);   // 69632 B

__device__ __attribute__((always_inline)) void gemm_body(int bx, int which,
    const ushort_t* __restrict__ Xh, const ushort_t* __restrict__ Xl,
    const ushort_t* __restrict__ Wfh, const ushort_t* __restrict__ Wfl,
    int lw,
    const float* __restrict__ b0, const float* __restrict__ b1,
    const float* __restrict__ b2, const float* __restrict__ b3,
    char* __restrict__ Oq, char* __restrict__ Okv,
    ushort_t* __restrict__ Os) {
    extern __shared__ ushort_t sm[];
    ushort_t* XhS = sm;                 // [128][XS]
    ushort_t* XlS = sm + 128 * XS;      // [128][XS]
    const ushort_t* wfh = Wfh + (size_t)(lw + which) * 16384;
    const ushort_t* wfl = Wfl + (size_t)(lw + which) * 16384;
    const float* bias = (which == 0) ? b0 : (which == 1) ? b1 : (which == 2) ? b2 : b3;
    // output routing: 0=q int8(128B rows) 1=k int8(kv+0) 2=v fp8(kv+128) 3=s bf16
    char* O8 = (which == 0) ? Oq : (which == 1) ? Okv : Okv + 128;
    int   o8str = (which == 0) ? 128 : 256;

    int w = threadIdx.x >> 6;
    int lane = threadIdx.x & 63;
    int quad = lane >> 4, ln = lane & 15;
    int n0 = w * 32;

    bf16x8 bh[2][4], bl[2][4];
#pragma unroll
    for (int ct = 0; ct < 2; ++ct)
#pragma unroll
        for (int kc = 0; kc < 4; ++kc) {
            int off = (w * 512 + ct * 256 + kc * 64 + lane) * 8;
            bh[ct][kc] = *(const bf16x8*)(wfh + off);
            bl[ct][kc] = *(const bf16x8*)(wfl + off);
        }
    float bias0 = bias[n0 + ln];
    float bias1 = bias[n0 + 16 + ln];

    int rowBase = bx * 128;
    int trow = threadIdx.x >> 4;          // staging: 16 rows per instruction
    int tcol = (threadIdx.x & 15) * 8;    // 16B per lane, contiguous per row

    // ---- full-tile stage: 16 loads per thread, issued back-to-back ----
#pragma unroll
    for (int rr = 0; rr < 8; ++rr) {
        int lrow = trow + rr * 16;
        int grow = min(rowBase + lrow, Nn - 1);
        *(ushort8*)(&XhS[lrow * XS + tcol]) =
            *(const ushort8*)(Xh + (size_t)grow * 128 + tcol);
        *(ushort8*)(&XlS[lrow * XS + tcol]) =
            *(const ushort8*)(Xl + (size_t)grow * 128 + tcol);
    }
    __syncthreads();

    // ---- dense compute: 8 row-tiles, no further barriers ----
#pragma unroll 2
    for (int rt = 0; rt < 8; ++rt) {
        const ushort_t* ph = &XhS[(rt * 16 + ln) * XS + quad * 8];
        const ushort_t* pl = &XlS[(rt * 16 + ln) * XS + quad * 8];
        bf16x8 ah[4], al[4];
#pragma unroll
        for (int kc = 0; kc < 4; ++kc) {
            ah[kc] = *(const bf16x8*)(ph + kc * 32);
            al[kc] = *(const bf16x8*)(pl + kc * 32);
        }
        f32x4 acc00 = {0.f,0.f,0.f,0.f}, acc01 = {0.f,0.f,0.f,0.f};
        f32x4 acc10 = {0.f,0.f,0.f,0.f}, acc11 = {0.f,0.f,0.f,0.f};
#pragma unroll
        for (int kc = 0; kc < 2; ++kc) {
            int k2 = kc + 2;
            acc00 = __builtin_amdgcn_mfma_f32_16x16x32_bf16(ah[kc], bh[0][kc], acc00, 0, 0, 0);
            acc01 = __builtin_amdgcn_mfma_f32_16x16x32_bf16(ah[kc], bh[1][kc], acc01, 0, 0, 0);
            acc10 = __builtin_amdgcn_mfma_f32_16x16x32_bf16(ah[k2], bh[0][k2], acc10, 0, 0, 0);
            acc11 = __builtin_amdgcn_mfma_f32_16x16x32_bf16(ah[k2], bh[1][k2], acc11, 0, 0, 0);
            acc00 = __builtin_amdgcn_mfma_f32_16x16x32_bf16(ah[kc], bl[0][kc], acc00, 0, 0, 0);
            acc01 = __builtin_amdgcn_mfma_f32_16x16x32_bf16(ah[kc], bl[1][kc], acc01, 0, 0, 0);
            acc10 = __builtin_amdgcn_mfma_f32_16x16x32_bf16(ah[k2], bl[0][k2], acc10, 0, 0, 0);
            acc11 = __builtin_amdgcn_mfma_f32_16x16x32_bf16(ah[k2], bl[1][k2], acc11, 0, 0, 0);
            acc00 = __builtin_amdgcn_mfma_f32_16x16x32_bf16(al[kc], bh[0][kc], acc00, 0, 0, 0);
            acc01 = __builtin_amdgcn_mfma_f32_16x16x32_bf16(al[kc], bh[1][kc], acc01, 0, 0, 0);
            acc10 = __builtin_amdgcn_mfma_f32_16x16x32_bf16(al[k2], bh[0][k2], acc10, 0, 0, 0);
            acc11 = __builtin_amdgcn_mfma_f32_16x16x32_bf16(al[k2], bh[1][k2], acc11, 0, 0, 0);
        }
        int m0 = rowBase + rt * 16;
        int orow0 = m0 + quad * 4;
        bool full = (orow0 + 3) < Nn;
#pragma unroll
        for (int reg = 0; reg < 4; ++reg) {
            int orow = orow0 + reg;
            if (full || orow < Nn) {
                float o0 = acc00[reg] + acc10[reg] + bias0;
                float o1 = acc01[reg] + acc11[reg] + bias1;
                if (which <= 1) {                 // q,k: int8 scale 16
                    size_t ob = (size_t)orow * o8str;
                    O8[ob + n0 + ln]      = q_i8(o0);
                    O8[ob + n0 + 16 + ln] = q_i8(o1);
                } else if (which == 2) {          // v: fp8
                    int pk = __builtin_amdgcn_cvt_pk_fp8_f32(o0, o1, 0, false);
                    size_t ob = (size_t)orow * 256;
                    O8[ob + n0 + ln]      = (char)(pk & 0xff);
                    O8[ob + n0 + 16 + ln] = (char)((pk >> 8) & 0xff);
                } else {                          // s: bf16
                    size_t ob = (size_t)orow * 128;
                    Os[ob + n0 + ln]      = f2bf(o0);
                    Os[ob + n0 + 16 + ln] = f2bf(o1);
                }
            }
        }
    }
}

// layer-1 gemm (1D grid + XCD-group swizzle)
__global__ __launch_bounds__(256) void gemm_mfma_kernel(
    const ushort_t* __restrict__ Xh, const ushort_t* __restrict__ Xl,
    const ushort_t* __restrict__ Wfh, const ushort_t* __restrict__ Wfl,
    int lw,
    const float* __restrict__ b0, const float* __restrict__ b1,
    const float* __restrict__ b2, const float* __restrict__ b3,
    char* __restrict__ Oq, char* __restrict__ Okv,
    ushort_t* __restrict__ Os) {
    int wi = xcd_group(blockIdx.x, NT * 4);
    gemm_body(wi >> 2, wi & 3, Xh, Xl, Wfh, Wfl, lw, b0, b1, b2, b3, Oq, Okv, Os);
}

// layer-0 gemm fused with ATOMIC-FREE edge scatter (4 edges/thread)
constexpr int G0B = NT * 4;
constexpr int EB4 = (Ee + 1023) / 1024;   // 782 scatter blocks

__global__ __launch_bounds__(256) void gemm0_scatter_kernel(
    const ushort_t* __restrict__ Xh, const ushort_t* __restrict__ Xl,
    const ushort_t* __restrict__ Wfh, const ushort_t* __restrict__ Wfl,
    const float* __restrict__ b0, const float* __restrict__ b1,
    const float* __restrict__ b2, const float* __restrict__ b3,
    char* __restrict__ Oq, char* __restrict__ Okv, ushort_t* __restrict__ Os,
    const int* __restrict__ src, const int* __restrict__ dst,
    const int* __restrict__ offsets, const int* __restrict__ rank,
    const int* __restrict__ blockSums,
    int* __restrict__ sorted_src) {
    int b = blockIdx.x;
    if (b >= G0B) {
        int e0 = ((b - G0B) * 256 + threadIdx.x) * 4;
        if (e0 >= Ee) return;                       // Ee % 4 == 0
        int4 d = *(const int4*)(dst + e0);
        int4 r = *(const int4*)(rank + e0);
        int4 s = *(const int4*)(src + e0);
        int o0 = offsets[d.x] + blockSums[d.x >> 8];
        int o1 = offsets[d.y] + blockSums[d.y >> 8];
        int o2 = offsets[d.z] + blockSums[d.z >> 8];
        int o3 = offsets[d.w] + blockSums[d.w >> 8];
        sorted_src[o0 + r.x] = s.x;
        sorted_src[o1 + r.y] = s.y;
        sorted_src[o2 + r.z] = s.z;
        sorted_src[o3 + r.w] = s.w;
        return;
    }
    int wi = xcd_group(b, G0B);
    gemm_body(wi >> 2, wi & 3, Xh, Xl, Wfh, Wfl, 0, b0, b1, b2, b3, Oq, Okv, Os);
}

// ---------------- fused per-node attention (int8 q.k dot, fp8 v) ------------

__global__ __launch_bounds__(256) void attn_kernel(const char* __restrict__ q,
                                                   const char* __restrict__ kv,
                                                   const ushort_t* __restrict__ s,
                                                   const int* __restrict__ offsets,
                                                   const int* __restrict__ blockSums,
                                                   const int* __restrict__ sorted_src,
                                                   ushort_t* __restrict__ oh,
                                                   ushort_t* __restrict__ ol,
                                                   int write_split) {
    __shared__ float merge[4][8][128];      // 16 KB: per-wave [group][dim] partials
    int warp = threadIdx.x >> 6;
    int wid = blockIdx.x * 4 + warp;
    if (wid >= Nn) return;
    int lane = threadIdx.x & 63;
    int g = lane >> 3;           // edge parity group 0..7
    int gl = lane & 7;           // dim chunk: [gl*16, gl*16+16)
    int4 qw = *(const int4*)(q + (size_t)wid * 128 + gl * 16);   // 16 int8 dims
    int beg = offsets[wid] + blockSums[wid >> 8];
    int end = (wid == Nn - 1) ? Ee
                              : offsets[wid + 1] + blockSums[(wid + 1) >> 8];

    float l = 0.f;
    f32x4 accq[4];
#pragma unroll
    for (int j = 0; j < 4; ++j) accq[j] = (f32x4){0.f, 0.f, 0.f, 0.f};
    f32x2* acc = (f32x2*)accq;   // acc[j] = dims (gl*16 + 2j, gl*16 + 2j+1)

    // depth-2 pipeline: sidx two iterations ahead, kv one ahead
    int e = beg + g;
    int s0 = (e < end) ? sorted_src[e] : 0;
    int s1 = (e + 8 < end) ? sorted_src[e + 8] : 0;
    const char* kvp0 = kv + (size_t)s0 * 256 + gl * 16;
    int4 kw = *(const int4*)(kvp0);
    int4 vw = *(const int4*)(kvp0 + 128);

    for (; e < end; e += 8) {
        // issue next iteration's kv load + next-next sidx load first
        const char* kvp1 = kv + (size_t)s1 * 256 + gl * 16;
        int4 kw1 = *(const int4*)(kvp1);
        int4 vw1 = *(const int4*)(kvp1 + 128);
        int s2 = (e + 16 < end) ? sorted_src[e + 16] : 0;

        int di = __builtin_amdgcn_sdot4(qw.x, kw.x, 0, false);
        di = __builtin_amdgcn_sdot4(qw.y, kw.y, di, false);
        di = __builtin_amdgcn_sdot4(qw.z, kw.z, di, false);
        di = __builtin_amdgcn_sdot4(qw.w, kw.w, di, false);
        di += __shfl_xor(di, 1, 64);
        di += __shfl_xor(di, 2, 64);
        di += __shfl_xor(di, 4, 64);
        float pw = __expf((float)di * ISC);
        l += pw;
        f32x2 pw2 = {pw, pw};
        {
            f32x2 lo, hi;
            lo = __builtin_amdgcn_cvt_pk_f32_fp8(vw.x, false);
            hi = __builtin_amdgcn_cvt_pk_f32_fp8(vw.x, true);
            acc[0] += pw2 * lo; acc[1] += pw2 * hi;
            lo = __builtin_amdgcn_cvt_pk_f32_fp8(vw.y, false);
            hi = __builtin_amdgcn_cvt_pk_f32_fp8(vw.y, true);
            acc[2] += pw2 * lo; acc[3] += pw2 * hi;
            lo = __builtin_amdgcn_cvt_pk_f32_fp8(vw.z, false);
            hi = __builtin_amdgcn_cvt_pk_f32_fp8(vw.z, true);
            acc[4] += pw2 * lo; acc[5] += pw2 * hi;
            lo = __builtin_amdgcn_cvt_pk_f32_fp8(vw.w, false);
            hi = __builtin_amdgcn_cvt_pk_f32_fp8(vw.w, true);
            acc[6] += pw2 * lo; acc[7] += pw2 * hi;
        }
        kw = kw1; vw = vw1; s1 = s2;
    }

    // ---- merge over the 8 edge groups via per-wave LDS transpose ----
    float* mrow = &merge[warp][g][gl * 16];
    *(f32x4*)(mrow + 0)  = accq[0];
    *(f32x4*)(mrow + 4)  = accq[1];
    *(f32x4*)(mrow + 8)  = accq[2];
    *(f32x4*)(mrow + 12) = accq[3];
    // wave-local fence: drain DS writes before cross-lane reads
    __builtin_amdgcn_sched_barrier(0);
    asm volatile("s_waitcnt lgkmcnt(0)" ::: "memory");
    __builtin_amdgcn_sched_barrier(0);

    // l is identical across the 8 gl lanes of a group; sum over groups only
    l += __shfl_xor(l, 8, 64);
    l += __shfl_xor(l, 16, 64);
    l += __shfl_xor(l, 32, 64);

    int d0 = lane << 1;          // this lane owns dims d0, d0+1
    f32x2 sum = {0.f, 0.f};
#pragma unroll
    for (int gg = 0; gg < 8; ++gg) sum += *(f32x2*)(&merge[warp][gg][d0]);

    float inv = (l > 0.f) ? (1.0f / l) : 0.f;   // deg==0 -> pure skip
    ushort2 sv = *(const ushort2*)(s + (size_t)wid * 128 + d0);
    float o0 = fmaxf(sum.x * inv + bf2f(sv.x), 0.f);
    float o1 = fmaxf(sum.y * inv + bf2f(sv.y), 0.f);
    ushort2 h;
    h.x = f2bf(o0); h.y = f2bf(o1);
    *(ushort2*)(oh + (size_t)wid * 128 + d0) = h;
    if (write_split) {
        ushort2 lo2;
        lo2.x = f2bf(o0 - bf2f(h.x));
        lo2.y = f2bf(o1 - bf2f(h.y));
        *(ushort2*)(ol + (size_t)wid * 128 + d0) = lo2;
    }
}

// ---------------- pooling (bf16 h, coalesced rows, LDS partials) ----------------

__global__ __launch_bounds__(256) void pool_kernel(const ushort_t* __restrict__ hb,
                                                   const int* __restrict__ batch,
                                                   float* __restrict__ pooled) {
    __shared__ float ps[4][128];
    int n0 = blockIdx.x * 256;
    int t = threadIdx.x;
    int lane32 = t & 31, rowgrp = t >> 5;
    for (int i = t; i < 512; i += 256) ((float*)ps)[i] = 0.f;
    __syncthreads();
    int gfirst = batch[min(n0, Nn - 1)];
    int d0 = lane32 * 4;
    float a0 = 0.f, a1 = 0.f, a2 = 0.f, a3 = 0.f;
    int curg = -1;
    for (int rr = 0; rr < 32; ++rr) {
        int n = n0 + rowgrp + rr * 8;
        if (n >= Nn) break;
        int g = batch[n];
        if (g != curg) {
            if (curg >= 0) {
                int slot = curg - gfirst;
                if (slot < 4) {
                    atomicAdd(&ps[slot][d0],     a0);
                    atomicAdd(&ps[slot][d0 + 1], a1);
                    atomicAdd(&ps[slot][d0 + 2], a2);
                    atomicAdd(&ps[slot][d0 + 3], a3);
                } else {
                    atomicAdd(&pooled[curg * Dd + d0],     a0);
                    atomicAdd(&pooled[curg * Dd + d0 + 1], a1);
                    atomicAdd(&pooled[curg * Dd + d0 + 2], a2);
                    atomicAdd(&pooled[curg * Dd + d0 + 3], a3);
                }
                a0 = a1 = a2 = a3 = 0.f;
            }
            curg = g;
        }
        ushort4 hv = *(const ushort4*)(hb + (size_t)n * 128 + d0);
        a0 += bf2f(hv.x); a1 += bf2f(hv.y); a2 += bf2f(hv.z); a3 += bf2f(hv.w);
    }
    if (curg >= 0) {
        int slot = curg - gfirst;
        if (slot < 4) {
            atomicAdd(&ps[slot][d0],     a0);
            atomicAdd(&ps[slot][d0 + 1], a1);
            atomicAdd(&ps[slot][d0 + 2], a2);
            atomicAdd(&ps[slot][d0 + 3], a3);
        } else {
            atomicAdd(&pooled[curg * Dd + d0],     a0);
            atomicAdd(&pooled[curg * Dd + d0 + 1], a1);
            atomicAdd(&pooled[curg * Dd + d0 + 2], a2);
            atomicAdd(&pooled[curg * Dd + d0 + 3], a3);
        }
    }
    __syncthreads();
    int glast = batch[min(n0 + 255, Nn - 1)];
    int nslots = min(glast - gfirst + 1, 4);
    for (int i = t; i < nslots * 128; i += 256) {
        int slot = i >> 7, d = i & 127;
        atomicAdd(&pooled[(gfirst + slot) * Dd + d], ps[slot][d]);
    }
}

__global__ __launch_bounds__(64) void mlp_kernel(const float* __restrict__ pooled,
                                                 const int* __restrict__ startg,
                                                 const int* __restrict__ endg,
                                                 const float* __restrict__ Wc1,
                                                 const float* __restrict__ bc1,
                                                 const float* __restrict__ Wc2,
                                                 const float* __restrict__ bc2,
                                                 float* __restrict__ out) {
    __shared__ float pm[128];
    __shared__ float hid[64];
    int g = blockIdx.x, t = threadIdx.x;   // 64 threads
    float cnt = fmaxf((float)(endg[g] - startg[g]), 1.0f);
    float invc = 1.0f / cnt;
    pm[t]      = pooled[g * 128 + t] * invc;
    pm[t + 64] = pooled[g * 128 + 64 + t] * invc;
    __syncthreads();
    float acc = bc1[t];
    for (int i = 0; i < 128; ++i) acc += pm[i] * Wc1[t * 128 + i];
    hid[t] = fmaxf(acc, 0.f);
    __syncthreads();
    if (t < 2) {
        float a = bc2[t];
        for (int i = 0; i < 64; ++i) a += hid[i] * Wc2[t * 64 + i];
        out[g * 2 + t] = a;
    }
}

// ---------------- launch ----------------

extern "C" void kernel_launch(void* const* d_in, const int* in_sizes, int n_in,
                              void* d_out, int out_size, void* d_ws, size_t ws_size,
                              hipStream_t stream) {
    const float* x   = (const float*)d_in[0];
    const int*   ei  = (const int*)d_in[1];
    const int* batch = (const int*)d_in[2];
    const float* W[2][4];
    const float* B[2][4];
    for (int l = 0; l < 2; ++l) {
        for (int j = 0; j < 4; ++j) W[l][j] = (const float*)d_in[3 + l * 8 + j];
        for (int j = 0; j < 4; ++j) B[l][j] = (const float*)d_in[3 + l * 8 + 4 + j];
    }
    const float* Wc1 = (const float*)d_in[19];
    const float* bc1 = (const float*)d_in[20];
    const float* Wc2 = (const float*)d_in[21];
    const float* bc2 = (const float*)d_in[22];
    float* out = (float*)d_out;

    const int* src = ei;        // edge_index[0]
    const int* dst = ei + Ee;   // edge_index[1]

    char* p = (char*)d_ws;
    auto alloc = [&](size_t bytes) {
        void* r = (void*)p;
        p += (bytes + 255) & ~(size_t)255;
        return r;
    };
    char*     q  = (char*)alloc((size_t)Nn * 128);          // int8 (scale 16)
    char*     kv = (char*)alloc((size_t)Nn * 256);          // [k_int8|v_fp8]
    ushort_t* ss = (ushort_t*)alloc((size_t)Nn * 128 * 2);  // bf16
    ushort_t* hb = (ushort_t*)alloc((size_t)Nn * 128 * 2);  // bf16 layer-2 h
    ushort_t* Xh = (ushort_t*)alloc((size_t)Nn * 128 * 2);
    ushort_t* Xl = (ushort_t*)alloc((size_t)Nn * 128 * 2);
    ushort_t* Wfh = (ushort_t*)alloc((size_t)8 * 16384 * 2);
    ushort_t* Wfl = (ushort_t*)alloc((size_t)8 * 16384 * 2);
    char* zbase = p;  // region zeroed each launch
    int*   counts = (int*)alloc((size_t)Nn * CPAD * 4);     // 64B-padded counters
    int*   startg = (int*)alloc(Gg * 4);
    int*   endg   = (int*)alloc(Gg * 4);
    float* pooled = (float*)alloc(Gg * Dd * 4);
    size_t zbytes = (size_t)(p - zbase);
    int* offsets    = (int*)alloc((size_t)(Nn + 1) * 4);
    int* rank       = (int*)alloc((size_t)Ee * 4);
    int* blockSums  = (int*)alloc(256 * 4);
    int* sorted_src = (int*)alloc((size_t)Ee * 4);

    hipMemsetAsync(zbase, 0, zbytes, stream);

    constexpr int NB = (Nn + 255) / 256;  // 196 scan blocks

    // prep: hist(+rank) + bounds + convw + convx (independent, one launch)
    prep_kernel<<<EB8 + NBD + CWB + CXB, 256, 0, stream>>>(
        dst, counts, rank, batch, startg, endg,
        W[0][0], W[0][1], W[0][2], W[0][3], W[1][0], W[1][1], W[1][2], W[1][3],
        Wfh, Wfl, x, Xh, Xl);
    scan1_kernel<<<NB, 256, 0, stream>>>(counts, offsets, blockSums);
    scan2_kernel<<<1, 256, 0, stream>>>(blockSums, NB);
    // scan3 folded into consumers (offsets[i] + blockSums[i>>8])

    // layer-0 gemm fused with atomic-free scatter
    gemm0_scatter_kernel<<<G0B + EB4, 256, GEMM_LDS, stream>>>(
        Xh, Xl, Wfh, Wfl, B[0][0], B[0][1], B[0][2], B[0][3],
        q, kv, ss, src, dst, offsets, rank, blockSums, sorted_src);

    // layer-0 attn writes split-bf16 h straight into Xh/Xl
    attn_kernel<<<(Nn + 3) / 4, 256, 0, stream>>>(q, kv, ss, offsets, blockSums,
                                                  sorted_src, Xh, Xl, 1);
    // layer 1 (1D grid + XCD-group swizzle)
    gemm_mfma_kernel<<<NT * 4, 256, GEMM_LDS, stream>>>(Xh, Xl, Wfh, Wfl, 4,
                                                        B[1][0], B[1][1], B[1][2], B[1][3],
                                                        q, kv, ss);
    attn_kernel<<<(Nn + 3) / 4, 256, 0, stream>>>(q, kv, ss, offsets, blockSums,
                                                  sorted_src, hb, hb, 0);

    pool_kernel<<<(Nn + 255) / 256, 256, 0, stream>>>(hb, batch, pooled);
    mlp_kernel<<<Gg, 64, 0, stream>>>(pooled, startg, endg, Wc1, bc1, Wc2, bc2, out);
}

// Round 12
// 298.419 us; speedup vs baseline: 1.0515x; 1.0515x over previous
//
#include <hip/hip_runtime.h>
#include <math.h>

typedef __bf16 bf16x8 __attribute__((ext_vector_type(8)));
typedef float  f32x4  __attribute__((ext_vector_type(4)));
typedef float  f32x2  __attribute__((ext_vector_type(2)));
typedef unsigned short ushort_t;
typedef unsigned short ushort8 __attribute__((ext_vector_type(8)));

// Problem constants (fixed by the reference).
constexpr int Nn = 50000;   // nodes
constexpr int Ee = 800000;  // edges
constexpr int Dd = 128;     // feature dim
constexpr int Gg = 64;      // graphs
constexpr float SCALE = 0.08838834764831845f; // 1/sqrt(128)
constexpr float QS    = 16.0f;                 // int8 quant scale for q,k
constexpr float ISC   = SCALE / (QS * QS);     // int-dot -> alpha

constexpr int CPAD = 16;    // counts stride: 1 counter per 64B line (R7: confirmed
                            // memory-side atomics serialize per granule)

__device__ inline ushort_t f2bf(float f) {
    unsigned u = __float_as_uint(f);
    unsigned r = (u + 0x7FFF + ((u >> 16) & 1)) >> 16;   // RNE truncate to bf16
    return (ushort_t)r;
}
__device__ inline float bf2f(ushort_t b) { return __uint_as_float(((unsigned)b) << 16); }

__device__ inline char q_i8(float f) {
    int v = (int)rintf(f * QS);
    v = max(-127, min(127, v));
    return (char)v;
}

// bijective XCD-grouping swizzle (m204 form): blockIdx b round-robins XCDs
// (xcd = b%8); remap so each XCD owns a CONTIGUOUS work-id range -> the 4
// variant-blocks of a row-tile (adjacent work ids) land on the SAME XCD L2.
// R8 counter evidence: gemm0 FETCH 56 -> 19.4 MB. KEEP.
__device__ inline int xcd_group(int b, int n) {
    int q = n >> 3, r = n & 7;
    int xcd = b & 7, idx = b >> 3;
    int base = (xcd < r) ? xcd * (q + 1) : r * (q + 1) + (xcd - r) * q;
    return base + idx;
}

// ---------------- fused prep: hist(+rank) + graph bounds + convw + convx ----

constexpr int EB8 = (Ee + 2047) / 2048; // 391 hist blocks (8 edges/thread)
constexpr int NBD = (Nn + 255) / 256;   // 196 bound blocks
constexpr int CWB = 64;                 // convw blocks
constexpr int N8  = Nn * Dd / 8;        // 800000 8-float chunks
constexpr int CXB = N8 / 256;           // 3125 convx blocks

__global__ __launch_bounds__(256) void prep_kernel(
    const int* __restrict__ dst, int* __restrict__ counts, int* __restrict__ rank,
    const int* __restrict__ batch, int* __restrict__ startg, int* __restrict__ endg,
    const float* w0, const float* w1, const float* w2, const float* w3,
    const float* w4, const float* w5, const float* w6, const float* w7,
    ushort_t* __restrict__ Wfh, ushort_t* __restrict__ Wfl,
    const float* __restrict__ x, ushort_t* __restrict__ Xh, ushort_t* __restrict__ Xl) {
    int b = blockIdx.x;
    if (b < EB8) {                                  // ---- histogram + rank, 8/thr
        int e0 = (b * 256 + threadIdx.x) * 8;
        if (e0 >= Ee) return;                       // Ee % 8 == 0 -> full groups
        int4 d0 = *(const int4*)(dst + e0);
        int4 d1 = *(const int4*)(dst + e0 + 4);
        int r0 = atomicAdd(&counts[d0.x * CPAD], 1);
        int r1 = atomicAdd(&counts[d0.y * CPAD], 1);
        int r2 = atomicAdd(&counts[d0.z * CPAD], 1);
        int r3 = atomicAdd(&counts[d0.w * CPAD], 1);
        int r4 = atomicAdd(&counts[d1.x * CPAD], 1);
        int r5 = atomicAdd(&counts[d1.y * CPAD], 1);
        int r6 = atomicAdd(&counts[d1.z * CPAD], 1);
        int r7 = atomicAdd(&counts[d1.w * CPAD], 1);
        *(int4*)(rank + e0)     = (int4){r0, r1, r2, r3};
        *(int4*)(rank + e0 + 4) = (int4){r4, r5, r6, r7};
    } else if (b < EB8 + NBD) {                     // ---- graph bounds
        int n = (b - EB8) * 256 + threadIdx.x;
        if (n >= Nn) return;
        int g = batch[n];
        if (n == Nn - 1 || batch[n + 1] != g) endg[g] = n + 1;
        if (n == 0 || batch[n - 1] != g) startg[g] = n;
    } else if (b < EB8 + NBD + CWB) {               // ---- fragment-order weights
        const float* ws[8] = {w0, w1, w2, w3, w4, w5, w6, w7};
        int b2 = b - (EB8 + NBD);
        int m = b2 >> 3;
        int tt = (b2 & 7) * 256 + threadIdx.x;      // 0..2047 fragment slots
        int lane = tt & 63;
        int ln = lane & 15, quad = lane >> 4;
        int n = (tt >> 9) * 32 + ((tt >> 8) & 1) * 16 + ln;
        int k0 = ((tt >> 6) & 3) * 32 + quad * 8;
        const float* srcp = ws[m] + n * 128 + k0;
        float4 a = *(const float4*)(srcp);
        float4 bb = *(const float4*)(srcp + 4);
        float e[8] = {a.x, a.y, a.z, a.w, bb.x, bb.y, bb.z, bb.w};
        ushort8 h, l;
#pragma unroll
        for (int j = 0; j < 8; ++j) {
            h[j] = f2bf(e[j]);
            l[j] = f2bf(e[j] - bf2f(h[j]));
        }
        size_t o = (size_t)m * 16384 + (size_t)tt * 8;
        *(ushort8*)(Wfh + o) = h;
        *(ushort8*)(Wfl + o) = l;
    } else {                                        // ---- split-bf16 convx (8 f/thr)
        int i = (b - (EB8 + NBD + CWB)) * 256 + threadIdx.x;
        if (i >= N8) return;
        float4 xa = ((const float4*)x)[i * 2];
        float4 xb = ((const float4*)x)[i * 2 + 1];
        float e[8] = {xa.x, xa.y, xa.z, xa.w, xb.x, xb.y, xb.z, xb.w};
        ushort8 h, l;
#pragma unroll
        for (int j = 0; j < 8; ++j) {
            h[j] = f2bf(e[j]);
            l[j] = f2bf(e[j] - bf2f(h[j]));
        }
        ((ushort8*)Xh)[i] = h;
        ((ushort8*)Xl)[i] = l;
    }
}

// ---------------- scans (CSR offsets) ----------------
// scan3 folded into consumers (offsets[i] + blockSums[i>>8]).

__global__ __launch_bounds__(256) void scan1_kernel(const int* __restrict__ counts,
                                                    int* __restrict__ offsets,
                                                    int* __restrict__ blockSums) {
    __shared__ int sh[256];
    int i = blockIdx.x * 256 + threadIdx.x;
    int v = (i < Nn) ? counts[i * CPAD] : 0;
    sh[threadIdx.x] = v;
    __syncthreads();
    for (int off = 1; off < 256; off <<= 1) {
        int t = (threadIdx.x >= off) ? sh[threadIdx.x - off] : 0;
        __syncthreads();
        sh[threadIdx.x] += t;
        __syncthreads();
    }
    if (i < Nn) offsets[i] = sh[threadIdx.x] - v;   // exclusive within block
    if (threadIdx.x == 255) blockSums[blockIdx.x] = sh[255];
}

__global__ __launch_bounds__(256) void scan2_kernel(int* __restrict__ blockSums, int nb) {
    __shared__ int sh[256];
    int t = threadIdx.x;
    int v = (t < nb) ? blockSums[t] : 0;
    sh[t] = v;
    __syncthreads();
    for (int off = 1; off < 256; off <<= 1) {
        int u = (t >= off) ? sh[t - off] : 0;
        __syncthreads();
        sh[t] += u;
        __syncthreads();
    }
    if (t < nb) blockSums[t] = sh[t] - v;           // exclusive across blocks
}

// ---------------- MFMA split-bf16 GEMM body: Y = X @ W^T + b ----------------
// Consolidated best config (R9, 298.6us): simple 32-row-chunk stage (full-tile
// and T14-prefetch variants both regressed -- kernel lives on TLP; any VGPR or
// LDS increase cuts resident waves), static 17KB LDS, XCD-group swizzle in
// callers, byte-store epilogue (wide-store swap falsified in R10: the WRITE
// amplification is the sorted_src scatter, not this epilogue).
// q,k out INT8 (scale 16); v out FP8-e4m3; s out bf16.

constexpr int XS = 136;   // LDS row stride in shorts (pad -> bank rotate)
constexpr int NT = (Nn + 127) / 128;    // 391 row tiles

__device__ __attribute__((always_inline)) void gemm_body(int bx, int which,
    const ushort_t* __restrict__ Xh, const ushort_t* __restrict__ Xl,
    const ushort_t* __restrict__ Wfh, const ushort_t* __restrict__ Wfl,
    int lw,
    const float* __restrict__ b0, const float* __restrict__ b1,
    const float* __restrict__ b2, const float* __restrict__ b3,
    char* __restrict__ Oq, char* __restrict__ Okv,
    ushort_t* __restrict__ Os) {
    __shared__ ushort_t XhS[32 * XS];
    __shared__ ushort_t XlS[32 * XS];
    const ushort_t* wfh = Wfh + (size_t)(lw + which) * 16384;
    const ushort_t* wfl = Wfl + (size_t)(lw + which) * 16384;
    const float* bias = (which == 0) ? b0 : (which == 1) ? b1 : (which == 2) ? b2 : b3;
    // output routing: 0=q int8(128B rows) 1=k int8(kv+0) 2=v fp8(kv+128) 3=s bf16
    char* O8 = (which == 0) ? Oq : (which == 1) ? Okv : Okv + 128;
    int   o8str = (which == 0) ? 128 : 256;

    int w = threadIdx.x >> 6;
    int lane = threadIdx.x & 63;
    int quad = lane >> 4, ln = lane & 15;
    int n0 = w * 32;

    bf16x8 bh[2][4], bl[2][4];
#pragma unroll
    for (int ct = 0; ct < 2; ++ct)
#pragma unroll
        for (int kc = 0; kc < 4; ++kc) {
            int off = (w * 512 + ct * 256 + kc * 64 + lane) * 8;
            bh[ct][kc] = *(const bf16x8*)(wfh + off);
            bl[ct][kc] = *(const bf16x8*)(wfl + off);
        }
    float bias0 = bias[n0 + ln];
    float bias1 = bias[n0 + 16 + ln];

    int rowBase = bx * 128;
    int trow = threadIdx.x >> 4;          // staging: 16 rows per instruction
    int tcol = (threadIdx.x & 15) * 8;    // 16B per lane, contiguous per row

    for (int chunk = 0; chunk < 4; ++chunk) {
        int cbase = rowBase + chunk * 32;
        __syncthreads();
#pragma unroll
        for (int rr = 0; rr < 2; ++rr) {
            int lrow = trow + rr * 16;
            int grow = min(cbase + lrow, Nn - 1);
            *(ushort8*)(&XhS[lrow * XS + tcol]) =
                *(const ushort8*)(Xh + (size_t)grow * 128 + tcol);
            *(ushort8*)(&XlS[lrow * XS + tcol]) =
                *(const ushort8*)(Xl + (size_t)grow * 128 + tcol);
        }
        __syncthreads();

#pragma unroll
        for (int rt = 0; rt < 2; ++rt) {
            const ushort_t* ph = &XhS[(rt * 16 + ln) * XS + quad * 8];
            const ushort_t* pl = &XlS[(rt * 16 + ln) * XS + quad * 8];
            bf16x8 ah[4], al[4];
#pragma unroll
            for (int kc = 0; kc < 4; ++kc) {
                ah[kc] = *(const bf16x8*)(ph + kc * 32);
                al[kc] = *(const bf16x8*)(pl + kc * 32);
            }
            f32x4 acc00 = {0.f,0.f,0.f,0.f}, acc01 = {0.f,0.f,0.f,0.f};
            f32x4 acc10 = {0.f,0.f,0.f,0.f}, acc11 = {0.f,0.f,0.f,0.f};
#pragma unroll
            for (int kc = 0; kc < 2; ++kc) {
                int k2 = kc + 2;
                acc00 = __builtin_amdgcn_mfma_f32_16x16x32_bf16(ah[kc], bh[0][kc], acc00, 0, 0, 0);
                acc01 = __builtin_amdgcn_mfma_f32_16x16x32_bf16(ah[kc], bh[1][kc], acc01, 0, 0, 0);
                acc10 = __builtin_amdgcn_mfma_f32_16x16x32_bf16(ah[k2], bh[0][k2], acc10, 0, 0, 0);
                acc11 = __builtin_amdgcn_mfma_f32_16x16x32_bf16(ah[k2], bh[1][k2], acc11, 0, 0, 0);
                acc00 = __builtin_amdgcn_mfma_f32_16x16x32_bf16(ah[kc], bl[0][kc], acc00, 0, 0, 0);
                acc01 = __builtin_amdgcn_mfma_f32_16x16x32_bf16(ah[kc], bl[1][kc], acc01, 0, 0, 0);
                acc10 = __builtin_amdgcn_mfma_f32_16x16x32_bf16(ah[k2], bl[0][k2], acc10, 0, 0, 0);
                acc11 = __builtin_amdgcn_mfma_f32_16x16x32_bf16(ah[k2], bl[1][k2], acc11, 0, 0, 0);
                acc00 = __builtin_amdgcn_mfma_f32_16x16x32_bf16(al[kc], bh[0][kc], acc00, 0, 0, 0);
                acc01 = __builtin_amdgcn_mfma_f32_16x16x32_bf16(al[kc], bh[1][kc], acc01, 0, 0, 0);
                acc10 = __builtin_amdgcn_mfma_f32_16x16x32_bf16(al[k2], bh[0][k2], acc10, 0, 0, 0);
                acc11 = __builtin_amdgcn_mfma_f32_16x16x32_bf16(al[k2], bh[1][k2], acc11, 0, 0, 0);
            }
            int m0 = cbase + rt * 16;
            int orow0 = m0 + quad * 4;
            bool full = (orow0 + 3) < Nn;
#pragma unroll
            for (int reg = 0; reg < 4; ++reg) {
                int orow = orow0 + reg;
                if (full || orow < Nn) {
                    float o0 = acc00[reg] + acc10[reg] + bias0;
                    float o1 = acc01[reg] + acc11[reg] + bias1;
                    if (which <= 1) {                 // q,k: int8 scale 16
                        size_t ob = (size_t)orow * o8str;
                        O8[ob + n0 + ln]      = q_i8(o0);
                        O8[ob + n0 + 16 + ln] = q_i8(o1);
                    } else if (which == 2) {          // v: fp8
                        int pk = __builtin_amdgcn_cvt_pk_fp8_f32(o0, o1, 0, false);
                        size_t ob = (size_t)orow * 256;
                        O8[ob + n0 + ln]      = (char)(pk & 0xff);
                        O8[ob + n0 + 16 + ln] = (char)((pk >> 8) & 0xff);
                    } else {                          // s: bf16
                        size_t ob = (size_t)orow * 128;
                        Os[ob + n0 + ln]      = f2bf(o0);
                        Os[ob + n0 + 16 + ln] = f2bf(o1);
                    }
                }
            }
        }
    }
}

// layer-1 gemm (1D grid + XCD-group swizzle)
__global__ __launch_bounds__(256) void gemm_mfma_kernel(
    const ushort_t* __restrict__ Xh, const ushort_t* __restrict__ Xl,
    const ushort_t* __restrict__ Wfh, const ushort_t* __restrict__ Wfl,
    int lw,
    const float* __restrict__ b0, const float* __restrict__ b1,
    const float* __restrict__ b2, const float* __restrict__ b3,
    char* __restrict__ Oq, char* __restrict__ Okv,
    ushort_t* __restrict__ Os) {
    int wi = xcd_group(blockIdx.x, NT * 4);
    gemm_body(wi >> 2, wi & 3, Xh, Xl, Wfh, Wfl, lw, b0, b1, b2, b3, Oq, Okv, Os);
}

// layer-0 gemm fused with ATOMIC-FREE edge scatter (4 edges/thread)
constexpr int G0B = NT * 4;
constexpr int EB4 = (Ee + 1023) / 1024;   // 782 scatter blocks

__global__ __launch_bounds__(256) void gemm0_scatter_kernel(
    const ushort_t* __restrict__ Xh, const ushort_t* __restrict__ Xl,
    const ushort_t* __restrict__ Wfh, const ushort_t* __restrict__ Wfl,
    const float* __restrict__ b0, const float* __restrict__ b1,
    const float* __restrict__ b2, const float* __restrict__ b3,
    char* __restrict__ Oq, char* __restrict__ Okv, ushort_t* __restrict__ Os,
    const int* __restrict__ src, const int* __restrict__ dst,
    const int* __restrict__ offsets, const int* __restrict__ rank,
    const int* __restrict__ blockSums,
    int* __restrict__ sorted_src) {
    int b = blockIdx.x;
    if (b >= G0B) {
        int e0 = ((b - G0B) * 256 + threadIdx.x) * 4;
        if (e0 >= Ee) return;                       // Ee % 4 == 0
        int4 d = *(const int4*)(dst + e0);
        int4 r = *(const int4*)(rank + e0);
        int4 s = *(const int4*)(src + e0);
        int o0 = offsets[d.x] + blockSums[d.x >> 8];
        int o1 = offsets[d.y] + blockSums[d.y >> 8];
        int o2 = offsets[d.z] + blockSums[d.z >> 8];
        int o3 = offsets[d.w] + blockSums[d.w >> 8];
        sorted_src[o0 + r.x] = s.x;
        sorted_src[o1 + r.y] = s.y;
        sorted_src[o2 + r.z] = s.z;
        sorted_src[o3 + r.w] = s.w;
        return;
    }
    int wi = xcd_group(b, G0B);
    gemm_body(wi >> 2, wi & 3, Xh, Xl, Wfh, Wfl, 0, b0, b1, b2, b3, Oq, Okv, Os);
}

// ---------------- fused per-node attention (int8 q.k dot, fp8 v) ------------

__global__ __launch_bounds__(256) void attn_kernel(const char* __restrict__ q,
                                                   const char* __restrict__ kv,
                                                   const ushort_t* __restrict__ s,
                                                   const int* __restrict__ offsets,
                                                   const int* __restrict__ blockSums,
                                                   const int* __restrict__ sorted_src,
                                                   ushort_t* __restrict__ oh,
                                                   ushort_t* __restrict__ ol,
                                                   int write_split) {
    __shared__ float merge[4][8][128];      // 16 KB: per-wave [group][dim] partials
    int warp = threadIdx.x >> 6;
    int wid = blockIdx.x * 4 + warp;
    if (wid >= Nn) return;
    int lane = threadIdx.x & 63;
    int g = lane >> 3;           // edge parity group 0..7
    int gl = lane & 7;           // dim chunk: [gl*16, gl*16+16)
    int4 qw = *(const int4*)(q + (size_t)wid * 128 + gl * 16);   // 16 int8 dims
    int beg = offsets[wid] + blockSums[wid >> 8];
    int end = (wid == Nn - 1) ? Ee
                              : offsets[wid + 1] + blockSums[(wid + 1) >> 8];

    float l = 0.f;
    f32x4 accq[4];
#pragma unroll
    for (int j = 0; j < 4; ++j) accq[j] = (f32x4){0.f, 0.f, 0.f, 0.f};
    f32x2* acc = (f32x2*)accq;   // acc[j] = dims (gl*16 + 2j, gl*16 + 2j+1)

    // depth-2 pipeline: sidx two iterations ahead, kv one ahead
    int e = beg + g;
    int s0 = (e < end) ? sorted_src[e] : 0;
    int s1 = (e + 8 < end) ? sorted_src[e + 8] : 0;
    const char* kvp0 = kv + (size_t)s0 * 256 + gl * 16;
    int4 kw = *(const int4*)(kvp0);
    int4 vw = *(const int4*)(kvp0 + 128);

    for (; e < end; e += 8) {
        // issue next iteration's kv load + next-next sidx load first
        const char* kvp1 = kv + (size_t)s1 * 256 + gl * 16;
        int4 kw1 = *(const int4*)(kvp1);
        int4 vw1 = *(const int4*)(kvp1 + 128);
        int s2 = (e + 16 < end) ? sorted_src[e + 16] : 0;

        int di = __builtin_amdgcn_sdot4(qw.x, kw.x, 0, false);
        di = __builtin_amdgcn_sdot4(qw.y, kw.y, di, false);
        di = __builtin_amdgcn_sdot4(qw.z, kw.z, di, false);
        di = __builtin_amdgcn_sdot4(qw.w, kw.w, di, false);
        di += __shfl_xor(di, 1, 64);
        di += __shfl_xor(di, 2, 64);
        di += __shfl_xor(di, 4, 64);
        float pw = __expf((float)di * ISC);
        l += pw;
        f32x2 pw2 = {pw, pw};
        {
            f32x2 lo, hi;
            lo = __builtin_amdgcn_cvt_pk_f32_fp8(vw.x, false);
            hi = __builtin_amdgcn_cvt_pk_f32_fp8(vw.x, true);
            acc[0] += pw2 * lo; acc[1] += pw2 * hi;
            lo = __builtin_amdgcn_cvt_pk_f32_fp8(vw.y, false);
            hi = __builtin_amdgcn_cvt_pk_f32_fp8(vw.y, true);
            acc[2] += pw2 * lo; acc[3] += pw2 * hi;
            lo = __builtin_amdgcn_cvt_pk_f32_fp8(vw.z, false);
            hi = __builtin_amdgcn_cvt_pk_f32_fp8(vw.z, true);
            acc[4] += pw2 * lo; acc[5] += pw2 * hi;
            lo = __builtin_amdgcn_cvt_pk_f32_fp8(vw.w, false);
            hi = __builtin_amdgcn_cvt_pk_f32_fp8(vw.w, true);
            acc[6] += pw2 * lo; acc[7] += pw2 * hi;
        }
        kw = kw1; vw = vw1; s1 = s2;
    }

    // ---- merge over the 8 edge groups via per-wave LDS transpose ----
    float* mrow = &merge[warp][g][gl * 16];
    *(f32x4*)(mrow + 0)  = accq[0];
    *(f32x4*)(mrow + 4)  = accq[1];
    *(f32x4*)(mrow + 8)  = accq[2];
    *(f32x4*)(mrow + 12) = accq[3];
    // wave-local fence: drain DS writes before cross-lane reads
    __builtin_amdgcn_sched_barrier(0);
    asm volatile("s_waitcnt lgkmcnt(0)" ::: "memory");
    __builtin_amdgcn_sched_barrier(0);

    // l is identical across the 8 gl lanes of a group; sum over groups only
    l += __shfl_xor(l, 8, 64);
    l += __shfl_xor(l, 16, 64);
    l += __shfl_xor(l, 32, 64);

    int d0 = lane << 1;          // this lane owns dims d0, d0+1
    f32x2 sum = {0.f, 0.f};
#pragma unroll
    for (int gg = 0; gg < 8; ++gg) sum += *(f32x2*)(&merge[warp][gg][d0]);

    float inv = (l > 0.f) ? (1.0f / l) : 0.f;   // deg==0 -> pure skip
    ushort2 sv = *(const ushort2*)(s + (size_t)wid * 128 + d0);
    float o0 = fmaxf(sum.x * inv + bf2f(sv.x), 0.f);
    float o1 = fmaxf(sum.y * inv + bf2f(sv.y), 0.f);
    ushort2 h;
    h.x = f2bf(o0); h.y = f2bf(o1);
    *(ushort2*)(oh + (size_t)wid * 128 + d0) = h;
    if (write_split) {
        ushort2 lo2;
        lo2.x = f2bf(o0 - bf2f(h.x));
        lo2.y = f2bf(o1 - bf2f(h.y));
        *(ushort2*)(ol + (size_t)wid * 128 + d0) = lo2;
    }
}

// ---------------- pooling (bf16 h, coalesced rows, LDS partials) ----------------

__global__ __launch_bounds__(256) void pool_kernel(const ushort_t* __restrict__ hb,
                                                   const int* __restrict__ batch,
                                                   float* __restrict__ pooled) {
    __shared__ float ps[4][128];
    int n0 = blockIdx.x * 256;
    int t = threadIdx.x;
    int lane32 = t & 31, rowgrp = t >> 5;
    for (int i = t; i < 512; i += 256) ((float*)ps)[i] = 0.f;
    __syncthreads();
    int gfirst = batch[min(n0, Nn - 1)];
    int d0 = lane32 * 4;
    float a0 = 0.f, a1 = 0.f, a2 = 0.f, a3 = 0.f;
    int curg = -1;
    for (int rr = 0; rr < 32; ++rr) {
        int n = n0 + rowgrp + rr * 8;
        if (n >= Nn) break;
        int g = batch[n];
        if (g != curg) {
            if (curg >= 0) {
                int slot = curg - gfirst;
                if (slot < 4) {
                    atomicAdd(&ps[slot][d0],     a0);
                    atomicAdd(&ps[slot][d0 + 1], a1);
                    atomicAdd(&ps[slot][d0 + 2], a2);
                    atomicAdd(&ps[slot][d0 + 3], a3);
                } else {
                    atomicAdd(&pooled[curg * Dd + d0],     a0);
                    atomicAdd(&pooled[curg * Dd + d0 + 1], a1);
                    atomicAdd(&pooled[curg * Dd + d0 + 2], a2);
                    atomicAdd(&pooled[curg * Dd + d0 + 3], a3);
                }
                a0 = a1 = a2 = a3 = 0.f;
            }
            curg = g;
        }
        ushort4 hv = *(const ushort4*)(hb + (size_t)n * 128 + d0);
        a0 += bf2f(hv.x); a1 += bf2f(hv.y); a2 += bf2f(hv.z); a3 += bf2f(hv.w);
    }
    if (curg >= 0) {
        int slot = curg - gfirst;
        if (slot < 4) {
            atomicAdd(&ps[slot][d0],     a0);
            atomicAdd(&ps[slot][d0 + 1], a1);
            atomicAdd(&ps[slot][d0 + 2], a2);
            atomicAdd(&ps[slot][d0 + 3], a3);
        } else {
            atomicAdd(&pooled[curg * Dd + d0],     a0);
            atomicAdd(&pooled[curg * Dd + d0 + 1], a1);
            atomicAdd(&pooled[curg * Dd + d0 + 2], a2);
            atomicAdd(&pooled[curg * Dd + d0 + 3], a3);
        }
    }
    __syncthreads();
    int glast = batch[min(n0 + 255, Nn - 1)];
    int nslots = min(glast - gfirst + 1, 4);
    for (int i = t; i < nslots * 128; i += 256) {
        int slot = i >> 7, d = i & 127;
        atomicAdd(&pooled[(gfirst + slot) * Dd + d], ps[slot][d]);
    }
}

__global__ __launch_bounds__(64) void mlp_kernel(const float* __restrict__ pooled,
                                                 const int* __restrict__ startg,
                                                 const int* __restrict__ endg,
                                                 const float* __restrict__ Wc1,
                                                 const float* __restrict__ bc1,
                                                 const float* __restrict__ Wc2,
                                                 const float* __restrict__ bc2,
                                                 float* __restrict__ out) {
    __shared__ float pm[128];
    __shared__ float hid[64];
    int g = blockIdx.x, t = threadIdx.x;   // 64 threads
    float cnt = fmaxf((float)(endg[g] - startg[g]), 1.0f);
    float invc = 1.0f / cnt;
    pm[t]      = pooled[g * 128 + t] * invc;
    pm[t + 64] = pooled[g * 128 + 64 + t] * invc;
    __syncthreads();
    float acc = bc1[t];
    for (int i = 0; i < 128; ++i) acc += pm[i] * Wc1[t * 128 + i];
    hid[t] = fmaxf(acc, 0.f);
    __syncthreads();
    if (t < 2) {
        float a = bc2[t];
        for (int i = 0; i < 64; ++i) a += hid[i] * Wc2[t * 64 + i];
        out[g * 2 + t] = a;
    }
}

// ---------------- launch ----------------

extern "C" void kernel_launch(void* const* d_in, const int* in_sizes, int n_in,
                              void* d_out, int out_size, void* d_ws, size_t ws_size,
                              hipStream_t stream) {
    const float* x   = (const float*)d_in[0];
    const int*   ei  = (const int*)d_in[1];
    const int* batch = (const int*)d_in[2];
    const float* W[2][4];
    const float* B[2][4];
    for (int l = 0; l < 2; ++l) {
        for (int j = 0; j < 4; ++j) W[l][j] = (const float*)d_in[3 + l * 8 + j];
        for (int j = 0; j < 4; ++j) B[l][j] = (const float*)d_in[3 + l * 8 + 4 + j];
    }
    const float* Wc1 = (const float*)d_in[19];
    const float* bc1 = (const float*)d_in[20];
    const float* Wc2 = (const float*)d_in[21];
    const float* bc2 = (const float*)d_in[22];
    float* out = (float*)d_out;

    const int* src = ei;        // edge_index[0]
    const int* dst = ei + Ee;   // edge_index[1]

    char* p = (char*)d_ws;
    auto alloc = [&](size_t bytes) {
        void* r = (void*)p;
        p += (bytes + 255) & ~(size_t)255;
        return r;
    };
    char*     q  = (char*)alloc((size_t)Nn * 128);          // int8 (scale 16)
    char*     kv = (char*)alloc((size_t)Nn * 256);          // [k_int8|v_fp8]
    ushort_t* ss = (ushort_t*)alloc((size_t)Nn * 128 * 2);  // bf16
    ushort_t* hb = (ushort_t*)alloc((size_t)Nn * 128 * 2);  // bf16 layer-2 h
    ushort_t* Xh = (ushort_t*)alloc((size_t)Nn * 128 * 2);
    ushort_t* Xl = (ushort_t*)alloc((size_t)Nn * 128 * 2);
    ushort_t* Wfh = (ushort_t*)alloc((size_t)8 * 16384 * 2);
    ushort_t* Wfl = (ushort_t*)alloc((size_t)8 * 16384 * 2);
    char* zbase = p;  // region zeroed each launch
    int*   counts = (int*)alloc((size_t)Nn * CPAD * 4);     // 64B-padded counters
    int*   startg = (int*)alloc(Gg * 4);
    int*   endg   = (int*)alloc(Gg * 4);
    float* pooled = (float*)alloc(Gg * Dd * 4);
    size_t zbytes = (size_t)(p - zbase);
    int* offsets    = (int*)alloc((size_t)(Nn + 1) * 4);
    int* rank       = (int*)alloc((size_t)Ee * 4);
    int* blockSums  = (int*)alloc(256 * 4);
    int* sorted_src = (int*)alloc((size_t)Ee * 4);

    hipMemsetAsync(zbase, 0, zbytes, stream);

    constexpr int NB = (Nn + 255) / 256;  // 196 scan blocks

    // prep: hist(+rank) + bounds + convw + convx (independent, one launch)
    prep_kernel<<<EB8 + NBD + CWB + CXB, 256, 0, stream>>>(
        dst, counts, rank, batch, startg, endg,
        W[0][0], W[0][1], W[0][2], W[0][3], W[1][0], W[1][1], W[1][2], W[1][3],
        Wfh, Wfl, x, Xh, Xl);
    scan1_kernel<<<NB, 256, 0, stream>>>(counts, offsets, blockSums);
    scan2_kernel<<<1, 256, 0, stream>>>(blockSums, NB);
    // scan3 folded into consumers (offsets[i] + blockSums[i>>8])

    // layer-0 gemm fused with atomic-free scatter
    gemm0_scatter_kernel<<<G0B + EB4, 256, 0, stream>>>(
        Xh, Xl, Wfh, Wfl, B[0][0], B[0][1], B[0][2], B[0][3],
        q, kv, ss, src, dst, offsets, rank, blockSums, sorted_src);

    // layer-0 attn writes split-bf16 h straight into Xh/Xl
    attn_kernel<<<(Nn + 3) / 4, 256, 0, stream>>>(q, kv, ss, offsets, blockSums,
                                                  sorted_src, Xh, Xl, 1);
    // layer 1 (1D grid + XCD-group swizzle)
    gemm_mfma_kernel<<<NT * 4, 256, 0, stream>>>(Xh, Xl, Wfh, Wfl, 4,
                                                 B[1][0], B[1][1], B[1][2], B[1][3],
                                                 q, kv, ss);
    attn_kernel<<<(Nn + 3) / 4, 256, 0, stream>>>(q, kv, ss, offsets, blockSums,
                                                  sorted_src, hb, hb, 0);

    pool_kernel<<<(Nn + 255) / 256, 256, 0, stream>>>(hb, batch, pooled);
    mlp_kernel<<<Gg, 64, 0, stream>>>(pooled, startg, endg, Wc1, bc1, Wc2, bc2, out);
}

// Round 13
// 297.151 us; speedup vs baseline: 1.0560x; 1.0043x over previous
//
#include <hip/hip_runtime.h>
#include <math.h>

typedef __bf16 bf16x8 __attribute__((ext_vector_type(8)));
typedef float  f32x4  __attribute__((ext_vector_type(4)));
typedef float  f32x2  __attribute__((ext_vector_type(2)));
typedef unsigned short ushort_t;
typedef unsigned short ushort8 __attribute__((ext_vector_type(8)));

// Problem constants (fixed by the reference).
constexpr int Nn = 50000;   // nodes
constexpr int Ee = 800000;  // edges
constexpr int Dd = 128;     // feature dim
constexpr int Gg = 64;      // graphs
constexpr float SCALE = 0.08838834764831845f; // 1/sqrt(128)
constexpr float QS    = 16.0f;                 // int8 quant scale for q,k
constexpr float ISC   = SCALE / (QS * QS);     // int-dot -> alpha

constexpr int CPAD = 16;    // counts stride: 1 counter per 64B line (R7: confirmed
                            // memory-side atomics serialize per granule)

__device__ inline ushort_t f2bf(float f) {
    unsigned u = __float_as_uint(f);
    unsigned r = (u + 0x7FFF + ((u >> 16) & 1)) >> 16;   // RNE truncate to bf16
    return (ushort_t)r;
}
__device__ inline float bf2f(ushort_t b) { return __uint_as_float(((unsigned)b) << 16); }

__device__ inline char q_i8(float f) {
    int v = (int)rintf(f * QS);
    v = max(-127, min(127, v));
    return (char)v;
}

// bijective XCD-grouping swizzle (m204 form): blockIdx b round-robins XCDs
// (xcd = b%8); remap so each XCD owns a CONTIGUOUS work-id range -> the 4
// variant-blocks of a row-tile (adjacent work ids) land on the SAME XCD L2.
// R8 counter evidence: gemm0 FETCH 56 -> 19.4 MB. KEEP.
__device__ inline int xcd_group(int b, int n) {
    int q = n >> 3, r = n & 7;
    int xcd = b & 7, idx = b >> 3;
    int base = (xcd < r) ? xcd * (q + 1) : r * (q + 1) + (xcd - r) * q;
    return base + idx;
}

// ---------------- fused prep: hist(+rank) + graph bounds + convw + convx ----

constexpr int EB8 = (Ee + 2047) / 2048; // 391 hist blocks (8 edges/thread)
constexpr int NBD = (Nn + 255) / 256;   // 196 bound blocks
constexpr int CWB = 64;                 // convw blocks
constexpr int N8  = Nn * Dd / 8;        // 800000 8-float chunks
constexpr int CXB = N8 / 256;           // 3125 convx blocks

__global__ __launch_bounds__(256) void prep_kernel(
    const int* __restrict__ dst, int* __restrict__ counts, int* __restrict__ rank,
    const int* __restrict__ batch, int* __restrict__ startg, int* __restrict__ endg,
    const float* w0, const float* w1, const float* w2, const float* w3,
    const float* w4, const float* w5, const float* w6, const float* w7,
    ushort_t* __restrict__ Wfh, ushort_t* __restrict__ Wfl,
    const float* __restrict__ x, ushort_t* __restrict__ Xh, ushort_t* __restrict__ Xl) {
    int b = blockIdx.x;
    if (b < EB8) {                                  // ---- histogram + rank, 8/thr
        int e0 = (b * 256 + threadIdx.x) * 8;
        if (e0 >= Ee) return;                       // Ee % 8 == 0 -> full groups
        int4 d0 = *(const int4*)(dst + e0);
        int4 d1 = *(const int4*)(dst + e0 + 4);
        int r0 = atomicAdd(&counts[d0.x * CPAD], 1);
        int r1 = atomicAdd(&counts[d0.y * CPAD], 1);
        int r2 = atomicAdd(&counts[d0.z * CPAD], 1);
        int r3 = atomicAdd(&counts[d0.w * CPAD], 1);
        int r4 = atomicAdd(&counts[d1.x * CPAD], 1);
        int r5 = atomicAdd(&counts[d1.y * CPAD], 1);
        int r6 = atomicAdd(&counts[d1.z * CPAD], 1);
        int r7 = atomicAdd(&counts[d1.w * CPAD], 1);
        *(int4*)(rank + e0)     = (int4){r0, r1, r2, r3};
        *(int4*)(rank + e0 + 4) = (int4){r4, r5, r6, r7};
    } else if (b < EB8 + NBD) {                     // ---- graph bounds
        int n = (b - EB8) * 256 + threadIdx.x;
        if (n >= Nn) return;
        int g = batch[n];
        if (n == Nn - 1 || batch[n + 1] != g) endg[g] = n + 1;
        if (n == 0 || batch[n - 1] != g) startg[g] = n;
    } else if (b < EB8 + NBD + CWB) {               // ---- fragment-order weights
        const float* ws[8] = {w0, w1, w2, w3, w4, w5, w6, w7};
        int b2 = b - (EB8 + NBD);
        int m = b2 >> 3;
        int tt = (b2 & 7) * 256 + threadIdx.x;      // 0..2047 fragment slots
        int lane = tt & 63;
        int ln = lane & 15, quad = lane >> 4;
        int n = (tt >> 9) * 32 + ((tt >> 8) & 1) * 16 + ln;
        int k0 = ((tt >> 6) & 3) * 32 + quad * 8;
        const float* srcp = ws[m] + n * 128 + k0;
        float4 a = *(const float4*)(srcp);
        float4 bb = *(const float4*)(srcp + 4);
        float e[8] = {a.x, a.y, a.z, a.w, bb.x, bb.y, bb.z, bb.w};
        ushort8 h, l;
#pragma unroll
        for (int j = 0; j < 8; ++j) {
            h[j] = f2bf(e[j]);
            l[j] = f2bf(e[j] - bf2f(h[j]));
        }
        size_t o = (size_t)m * 16384 + (size_t)tt * 8;
        *(ushort8*)(Wfh + o) = h;
        *(ushort8*)(Wfl + o) = l;
    } else {                                        // ---- split-bf16 convx (8 f/thr)
        int i = (b - (EB8 + NBD + CWB)) * 256 + threadIdx.x;
        if (i >= N8) return;
        float4 xa = ((const float4*)x)[i * 2];
        float4 xb = ((const float4*)x)[i * 2 + 1];
        float e[8] = {xa.x, xa.y, xa.z, xa.w, xb.x, xb.y, xb.z, xb.w};
        ushort8 h, l;
#pragma unroll
        for (int j = 0; j < 8; ++j) {
            h[j] = f2bf(e[j]);
            l[j] = f2bf(e[j] - bf2f(h[j]));
        }
        ((ushort8*)Xh)[i] = h;
        ((ushort8*)Xl)[i] = l;
    }
}

// ---------------- scans (CSR offsets) ----------------
// scan3 folded into consumers (offsets[i] + blockSums[i>>8]).

__global__ __launch_bounds__(256) void scan1_kernel(const int* __restrict__ counts,
                                                    int* __restrict__ offsets,
                                                    int* __restrict__ blockSums) {
    __shared__ int sh[256];
    int i = blockIdx.x * 256 + threadIdx.x;
    int v = (i < Nn) ? counts[i * CPAD] : 0;
    sh[threadIdx.x] = v;
    __syncthreads();
    for (int off = 1; off < 256; off <<= 1) {
        int t = (threadIdx.x >= off) ? sh[threadIdx.x - off] : 0;
        __syncthreads();
        sh[threadIdx.x] += t;
        __syncthreads();
    }
    if (i < Nn) offsets[i] = sh[threadIdx.x] - v;   // exclusive within block
    if (threadIdx.x == 255) blockSums[blockIdx.x] = sh[255];
}

__global__ __launch_bounds__(256) void scan2_kernel(int* __restrict__ blockSums, int nb) {
    __shared__ int sh[256];
    int t = threadIdx.x;
    int v = (t < nb) ? blockSums[t] : 0;
    sh[t] = v;
    __syncthreads();
    for (int off = 1; off < 256; off <<= 1) {
        int u = (t >= off) ? sh[t - off] : 0;
        __syncthreads();
        sh[t] += u;
        __syncthreads();
    }
    if (t < nb) blockSums[t] = sh[t] - v;           // exclusive across blocks
}

// ---------------- MFMA split-bf16 GEMM body: Y = X @ W^T + b ----------------
// Consolidated best config (R9/R12, 298.4us): simple 32-row-chunk stage,
// static 17KB LDS, XCD-group swizzle in callers, byte-store epilogue.
// q,k out INT8 (scale 16); v out FP8-e4m3; s out bf16.

constexpr int XS = 136;   // LDS row stride in shorts (pad -> bank rotate)
constexpr int NT = (Nn + 127) / 128;    // 391 row tiles

__device__ __attribute__((always_inline)) void gemm_body(int bx, int which,
    const ushort_t* __restrict__ Xh, const ushort_t* __restrict__ Xl,
    const ushort_t* __restrict__ Wfh, const ushort_t* __restrict__ Wfl,
    int lw,
    const float* __restrict__ b0, const float* __restrict__ b1,
    const float* __restrict__ b2, const float* __restrict__ b3,
    char* __restrict__ Oq, char* __restrict__ Okv,
    ushort_t* __restrict__ Os) {
    __shared__ ushort_t XhS[32 * XS];
    __shared__ ushort_t XlS[32 * XS];
    const ushort_t* wfh = Wfh + (size_t)(lw + which) * 16384;
    const ushort_t* wfl = Wfl + (size_t)(lw + which) * 16384;
    const float* bias = (which == 0) ? b0 : (which == 1) ? b1 : (which == 2) ? b2 : b3;
    // output routing: 0=q int8(128B rows) 1=k int8(kv+0) 2=v fp8(kv+128) 3=s bf16
    char* O8 = (which == 0) ? Oq : (which == 1) ? Okv : Okv + 128;
    int   o8str = (which == 0) ? 128 : 256;

    int w = threadIdx.x >> 6;
    int lane = threadIdx.x & 63;
    int quad = lane >> 4, ln = lane & 15;
    int n0 = w * 32;

    bf16x8 bh[2][4], bl[2][4];
#pragma unroll
    for (int ct = 0; ct < 2; ++ct)
#pragma unroll
        for (int kc = 0; kc < 4; ++kc) {
            int off = (w * 512 + ct * 256 + kc * 64 + lane) * 8;
            bh[ct][kc] = *(const bf16x8*)(wfh + off);
            bl[ct][kc] = *(const bf16x8*)(wfl + off);
        }
    float bias0 = bias[n0 + ln];
    float bias1 = bias[n0 + 16 + ln];

    int rowBase = bx * 128;
    int trow = threadIdx.x >> 4;          // staging: 16 rows per instruction
    int tcol = (threadIdx.x & 15) * 8;    // 16B per lane, contiguous per row

    for (int chunk = 0; chunk < 4; ++chunk) {
        int cbase = rowBase + chunk * 32;
        __syncthreads();
#pragma unroll
        for (int rr = 0; rr < 2; ++rr) {
            int lrow = trow + rr * 16;
            int grow = min(cbase + lrow, Nn - 1);
            *(ushort8*)(&XhS[lrow * XS + tcol]) =
                *(const ushort8*)(Xh + (size_t)grow * 128 + tcol);
            *(ushort8*)(&XlS[lrow * XS + tcol]) =
                *(const ushort8*)(Xl + (size_t)grow * 128 + tcol);
        }
        __syncthreads();

#pragma unroll
        for (int rt = 0; rt < 2; ++rt) {
            const ushort_t* ph = &XhS[(rt * 16 + ln) * XS + quad * 8];
            const ushort_t* pl = &XlS[(rt * 16 + ln) * XS + quad * 8];
            bf16x8 ah[4], al[4];
#pragma unroll
            for (int kc = 0; kc < 4; ++kc) {
                ah[kc] = *(const bf16x8*)(ph + kc * 32);
                al[kc] = *(const bf16x8*)(pl + kc * 32);
            }
            f32x4 acc00 = {0.f,0.f,0.f,0.f}, acc01 = {0.f,0.f,0.f,0.f};
            f32x4 acc10 = {0.f,0.f,0.f,0.f}, acc11 = {0.f,0.f,0.f,0.f};
#pragma unroll
            for (int kc = 0; kc < 2; ++kc) {
                int k2 = kc + 2;
                acc00 = __builtin_amdgcn_mfma_f32_16x16x32_bf16(ah[kc], bh[0][kc], acc00, 0, 0, 0);
                acc01 = __builtin_amdgcn_mfma_f32_16x16x32_bf16(ah[kc], bh[1][kc], acc01, 0, 0, 0);
                acc10 = __builtin_amdgcn_mfma_f32_16x16x32_bf16(ah[k2], bh[0][k2], acc10, 0, 0, 0);
                acc11 = __builtin_amdgcn_mfma_f32_16x16x32_bf16(ah[k2], bh[1][k2], acc11, 0, 0, 0);
                acc00 = __builtin_amdgcn_mfma_f32_16x16x32_bf16(ah[kc], bl[0][kc], acc00, 0, 0, 0);
                acc01 = __builtin_amdgcn_mfma_f32_16x16x32_bf16(ah[kc], bl[1][kc], acc01, 0, 0, 0);
                acc10 = __builtin_amdgcn_mfma_f32_16x16x32_bf16(ah[k2], bl[0][k2], acc10, 0, 0, 0);
                acc11 = __builtin_amdgcn_mfma_f32_16x16x32_bf16(ah[k2], bl[1][k2], acc11, 0, 0, 0);
                acc00 = __builtin_amdgcn_mfma_f32_16x16x32_bf16(al[kc], bh[0][kc], acc00, 0, 0, 0);
                acc01 = __builtin_amdgcn_mfma_f32_16x16x32_bf16(al[kc], bh[1][kc], acc01, 0, 0, 0);
                acc10 = __builtin_amdgcn_mfma_f32_16x16x32_bf16(al[k2], bh[0][k2], acc10, 0, 0, 0);
                acc11 = __builtin_amdgcn_mfma_f32_16x16x32_bf16(al[k2], bh[1][k2], acc11, 0, 0, 0);
            }
            int m0 = cbase + rt * 16;
            int orow0 = m0 + quad * 4;
            bool full = (orow0 + 3) < Nn;
#pragma unroll
            for (int reg = 0; reg < 4; ++reg) {
                int orow = orow0 + reg;
                if (full || orow < Nn) {
                    float o0 = acc00[reg] + acc10[reg] + bias0;
                    float o1 = acc01[reg] + acc11[reg] + bias1;
                    if (which <= 1) {                 // q,k: int8 scale 16
                        size_t ob = (size_t)orow * o8str;
                        O8[ob + n0 + ln]      = q_i8(o0);
                        O8[ob + n0 + 16 + ln] = q_i8(o1);
                    } else if (which == 2) {          // v: fp8
                        int pk = __builtin_amdgcn_cvt_pk_fp8_f32(o0, o1, 0, false);
                        size_t ob = (size_t)orow * 256;
                        O8[ob + n0 + ln]      = (char)(pk & 0xff);
                        O8[ob + n0 + 16 + ln] = (char)((pk >> 8) & 0xff);
                    } else {                          // s: bf16
                        size_t ob = (size_t)orow * 128;
                        Os[ob + n0 + ln]      = f2bf(o0);
                        Os[ob + n0 + 16 + ln] = f2bf(o1);
                    }
                }
            }
        }
    }
}

// layer-1 gemm (1D grid + XCD-group swizzle)
__global__ __launch_bounds__(256) void gemm_mfma_kernel(
    const ushort_t* __restrict__ Xh, const ushort_t* __restrict__ Xl,
    const ushort_t* __restrict__ Wfh, const ushort_t* __restrict__ Wfl,
    int lw,
    const float* __restrict__ b0, const float* __restrict__ b1,
    const float* __restrict__ b2, const float* __restrict__ b3,
    char* __restrict__ Oq, char* __restrict__ Okv,
    ushort_t* __restrict__ Os) {
    int wi = xcd_group(blockIdx.x, NT * 4);
    gemm_body(wi >> 2, wi & 3, Xh, Xl, Wfh, Wfl, lw, b0, b1, b2, b3, Oq, Okv, Os);
}

// layer-0 gemm fused with ATOMIC-FREE edge scatter (4 edges/thread)
constexpr int G0B = NT * 4;
constexpr int EB4 = (Ee + 1023) / 1024;   // 782 scatter blocks

__global__ __launch_bounds__(256) void gemm0_scatter_kernel(
    const ushort_t* __restrict__ Xh, const ushort_t* __restrict__ Xl,
    const ushort_t* __restrict__ Wfh, const ushort_t* __restrict__ Wfl,
    const float* __restrict__ b0, const float* __restrict__ b1,
    const float* __restrict__ b2, const float* __restrict__ b3,
    char* __restrict__ Oq, char* __restrict__ Okv, ushort_t* __restrict__ Os,
    const int* __restrict__ src, const int* __restrict__ dst,
    const int* __restrict__ offsets, const int* __restrict__ rank,
    const int* __restrict__ blockSums,
    int* __restrict__ sorted_src) {
    int b = blockIdx.x;
    if (b >= G0B) {
        int e0 = ((b - G0B) * 256 + threadIdx.x) * 4;
        if (e0 >= Ee) return;                       // Ee % 4 == 0
        int4 d = *(const int4*)(dst + e0);
        int4 r = *(const int4*)(rank + e0);
        int4 s = *(const int4*)(src + e0);
        int o0 = offsets[d.x] + blockSums[d.x >> 8];
        int o1 = offsets[d.y] + blockSums[d.y >> 8];
        int o2 = offsets[d.z] + blockSums[d.z >> 8];
        int o3 = offsets[d.w] + blockSums[d.w >> 8];
        sorted_src[o0 + r.x] = s.x;
        sorted_src[o1 + r.y] = s.y;
        sorted_src[o2 + r.z] = s.z;
        sorted_src[o3 + r.w] = s.w;
        return;
    }
    int wi = xcd_group(b, G0B);
    gemm_body(wi >> 2, wi & 3, Xh, Xl, Wfh, Wfl, 0, b0, b1, b2, b3, Oq, Okv, Os);
}

// ---------------- fused per-node attention (int8 q.k dot, fp8 v) ------------
// v3: TWO NODES PER WAVE. deg~16 with 8 edge-groups meant only 2 loop trips --
// per-node fixed costs (q load, LDS merge+drain, shfl reduces, epilogue)
// dominated, serialized ~49x per wave. Now each 32-lane half owns one node
// (4 edge groups x 8 dim lanes): fixed cost per node halved, l-merge 3->2
// shfls, group-sum 8->4 LDS reads, 8B epilogue stores. Same per-wave gather
// throughput (8 edges/iter, 128B-coalesced group reads). Nn = 6250*8 exactly.

__global__ __launch_bounds__(256) void attn_kernel(const char* __restrict__ q,
                                                   const char* __restrict__ kv,
                                                   const ushort_t* __restrict__ s,
                                                   const int* __restrict__ offsets,
                                                   const int* __restrict__ blockSums,
                                                   const int* __restrict__ sorted_src,
                                                   ushort_t* __restrict__ oh,
                                                   ushort_t* __restrict__ ol,
                                                   int write_split) {
    __shared__ float merge[4][2][4][128];   // 16 KB: [warp][half][group][dim]
    int warp = threadIdx.x >> 6;
    int lane = threadIdx.x & 63;
    int half = lane >> 5;        // which node of the wave's pair
    int l5 = lane & 31;
    int g = l5 >> 3;             // edge group 0..3
    int gl = l5 & 7;             // dim chunk: [gl*16, gl*16+16)
    int wid = blockIdx.x * 8 + warp * 2 + half;    // always < Nn (50000 = 6250*8)
    int4 qw = *(const int4*)(q + (size_t)wid * 128 + gl * 16);   // 16 int8 dims
    int beg = offsets[wid] + blockSums[wid >> 8];
    int end = (wid == Nn - 1) ? Ee
                              : offsets[wid + 1] + blockSums[(wid + 1) >> 8];

    float l = 0.f;
    f32x4 accq[4];
#pragma unroll
    for (int j = 0; j < 4; ++j) accq[j] = (f32x4){0.f, 0.f, 0.f, 0.f};
    f32x2* acc = (f32x2*)accq;   // acc[j] = dims (gl*16 + 2j, gl*16 + 2j+1)

    // depth-2 pipeline: sidx two iterations ahead, kv one ahead (step 4)
    int e = beg + g;
    int s0 = (e < end) ? sorted_src[e] : 0;
    int s1 = (e + 4 < end) ? sorted_src[e + 4] : 0;
    const char* kvp0 = kv + (size_t)s0 * 256 + gl * 16;
    int4 kw = *(const int4*)(kvp0);
    int4 vw = *(const int4*)(kvp0 + 128);

    for (; e < end; e += 4) {
        // issue next iteration's kv load + next-next sidx load first
        const char* kvp1 = kv + (size_t)s1 * 256 + gl * 16;
        int4 kw1 = *(const int4*)(kvp1);
        int4 vw1 = *(const int4*)(kvp1 + 128);
        int s2 = (e + 8 < end) ? sorted_src[e + 8] : 0;

        int di = __builtin_amdgcn_sdot4(qw.x, kw.x, 0, false);
        di = __builtin_amdgcn_sdot4(qw.y, kw.y, di, false);
        di = __builtin_amdgcn_sdot4(qw.z, kw.z, di, false);
        di = __builtin_amdgcn_sdot4(qw.w, kw.w, di, false);
        di += __shfl_xor(di, 1, 64);
        di += __shfl_xor(di, 2, 64);
        di += __shfl_xor(di, 4, 64);
        float pw = __expf((float)di * ISC);
        l += pw;
        f32x2 pw2 = {pw, pw};
        {
            f32x2 lo, hi;
            lo = __builtin_amdgcn_cvt_pk_f32_fp8(vw.x, false);
            hi = __builtin_amdgcn_cvt_pk_f32_fp8(vw.x, true);
            acc[0] += pw2 * lo; acc[1] += pw2 * hi;
            lo = __builtin_amdgcn_cvt_pk_f32_fp8(vw.y, false);
            hi = __builtin_amdgcn_cvt_pk_f32_fp8(vw.y, true);
            acc[2] += pw2 * lo; acc[3] += pw2 * hi;
            lo = __builtin_amdgcn_cvt_pk_f32_fp8(vw.z, false);
            hi = __builtin_amdgcn_cvt_pk_f32_fp8(vw.z, true);
            acc[4] += pw2 * lo; acc[5] += pw2 * hi;
            lo = __builtin_amdgcn_cvt_pk_f32_fp8(vw.w, false);
            hi = __builtin_amdgcn_cvt_pk_f32_fp8(vw.w, true);
            acc[6] += pw2 * lo; acc[7] += pw2 * hi;
        }
        kw = kw1; vw = vw1; s1 = s2;
    }

    // ---- merge over the 4 edge groups via per-half LDS transpose ----
    float* mrow = &merge[warp][half][g][gl * 16];
    *(f32x4*)(mrow + 0)  = accq[0];
    *(f32x4*)(mrow + 4)  = accq[1];
    *(f32x4*)(mrow + 8)  = accq[2];
    *(f32x4*)(mrow + 12) = accq[3];
    // wave-local fence: drain DS writes before cross-lane reads
    __builtin_amdgcn_sched_barrier(0);
    asm volatile("s_waitcnt lgkmcnt(0)" ::: "memory");
    __builtin_amdgcn_sched_barrier(0);

    // l is identical across the 8 gl lanes of a group; sum over 4 groups
    // (xor 8 toggles group bit0, xor 16 group bit1 -- stays within the half)
    l += __shfl_xor(l, 8, 64);
    l += __shfl_xor(l, 16, 64);

    int d0 = l5 << 2;            // this lane owns dims d0..d0+3
    f32x4 sum = {0.f, 0.f, 0.f, 0.f};
#pragma unroll
    for (int gg = 0; gg < 4; ++gg) sum += *(f32x4*)(&merge[warp][half][gg][d0]);

    float inv = (l > 0.f) ? (1.0f / l) : 0.f;   // deg==0 -> pure skip
    ushort4 sv = *(const ushort4*)(s + (size_t)wid * 128 + d0);
    float o[4];
    o[0] = fmaxf(sum[0] * inv + bf2f(sv.x), 0.f);
    o[1] = fmaxf(sum[1] * inv + bf2f(sv.y), 0.f);
    o[2] = fmaxf(sum[2] * inv + bf2f(sv.z), 0.f);
    o[3] = fmaxf(sum[3] * inv + bf2f(sv.w), 0.f);
    ushort4 h;
    h.x = f2bf(o[0]); h.y = f2bf(o[1]); h.z = f2bf(o[2]); h.w = f2bf(o[3]);
    *(ushort4*)(oh + (size_t)wid * 128 + d0) = h;
    if (write_split) {
        ushort4 lo4;
        lo4.x = f2bf(o[0] - bf2f(h.x));
        lo4.y = f2bf(o[1] - bf2f(h.y));
        lo4.z = f2bf(o[2] - bf2f(h.z));
        lo4.w = f2bf(o[3] - bf2f(h.w));
        *(ushort4*)(ol + (size_t)wid * 128 + d0) = lo4;
    }
}

// ---------------- pooling (bf16 h, coalesced rows, LDS partials) ----------------

__global__ __launch_bounds__(256) void pool_kernel(const ushort_t* __restrict__ hb,
                                                   const int* __restrict__ batch,
                                                   float* __restrict__ pooled) {
    __shared__ float ps[4][128];
    int n0 = blockIdx.x * 256;
    int t = threadIdx.x;
    int lane32 = t & 31, rowgrp = t >> 5;
    for (int i = t; i < 512; i += 256) ((float*)ps)[i] = 0.f;
    __syncthreads();
    int gfirst = batch[min(n0, Nn - 1)];
    int d0 = lane32 * 4;
    float a0 = 0.f, a1 = 0.f, a2 = 0.f, a3 = 0.f;
    int curg = -1;
    for (int rr = 0; rr < 32; ++rr) {
        int n = n0 + rowgrp + rr * 8;
        if (n >= Nn) break;
        int g = batch[n];
        if (g != curg) {
            if (curg >= 0) {
                int slot = curg - gfirst;
                if (slot < 4) {
                    atomicAdd(&ps[slot][d0],     a0);
                    atomicAdd(&ps[slot][d0 + 1], a1);
                    atomicAdd(&ps[slot][d0 + 2], a2);
                    atomicAdd(&ps[slot][d0 + 3], a3);
                } else {
                    atomicAdd(&pooled[curg * Dd + d0],     a0);
                    atomicAdd(&pooled[curg * Dd + d0 + 1], a1);
                    atomicAdd(&pooled[curg * Dd + d0 + 2], a2);
                    atomicAdd(&pooled[curg * Dd + d0 + 3], a3);
                }
                a0 = a1 = a2 = a3 = 0.f;
            }
            curg = g;
        }
        ushort4 hv = *(const ushort4*)(hb + (size_t)n * 128 + d0);
        a0 += bf2f(hv.x); a1 += bf2f(hv.y); a2 += bf2f(hv.z); a3 += bf2f(hv.w);
    }
    if (curg >= 0) {
        int slot = curg - gfirst;
        if (slot < 4) {
            atomicAdd(&ps[slot][d0],     a0);
            atomicAdd(&ps[slot][d0 + 1], a1);
            atomicAdd(&ps[slot][d0 + 2], a2);
            atomicAdd(&ps[slot][d0 + 3], a3);
        } else {
            atomicAdd(&pooled[curg * Dd + d0],     a0);
            atomicAdd(&pooled[curg * Dd + d0 + 1], a1);
            atomicAdd(&pooled[curg * Dd + d0 + 2], a2);
            atomicAdd(&pooled[curg * Dd + d0 + 3], a3);
        }
    }
    __syncthreads();
    int glast = batch[min(n0 + 255, Nn - 1)];
    int nslots = min(glast - gfirst + 1, 4);
    for (int i = t; i < nslots * 128; i += 256) {
        int slot = i >> 7, d = i & 127;
        atomicAdd(&pooled[(gfirst + slot) * Dd + d], ps[slot][d]);
    }
}

__global__ __launch_bounds__(64) void mlp_kernel(const float* __restrict__ pooled,
                                                 const int* __restrict__ startg,
                                                 const int* __restrict__ endg,
                                                 const float* __restrict__ Wc1,
                                                 const float* __restrict__ bc1,
                                                 const float* __restrict__ Wc2,
                                                 const float* __restrict__ bc2,
                                                 float* __restrict__ out) {
    __shared__ float pm[128];
    __shared__ float hid[64];
    int g = blockIdx.x, t = threadIdx.x;   // 64 threads
    float cnt = fmaxf((float)(endg[g] - startg[g]), 1.0f);
    float invc = 1.0f / cnt;
    pm[t]      = pooled[g * 128 + t] * invc;
    pm[t + 64] = pooled[g * 128 + 64 + t] * invc;
    __syncthreads();
    float acc = bc1[t];
    for (int i = 0; i < 128; ++i) acc += pm[i] * Wc1[t * 128 + i];
    hid[t] = fmaxf(acc, 0.f);
    __syncthreads();
    if (t < 2) {
        float a = bc2[t];
        for (int i = 0; i < 64; ++i) a += hid[i] * Wc2[t * 64 + i];
        out[g * 2 + t] = a;
    }
}

// ---------------- launch ----------------

extern "C" void kernel_launch(void* const* d_in, const int* in_sizes, int n_in,
                              void* d_out, int out_size, void* d_ws, size_t ws_size,
                              hipStream_t stream) {
    const float* x   = (const float*)d_in[0];
    const int*   ei  = (const int*)d_in[1];
    const int* batch = (const int*)d_in[2];
    const float* W[2][4];
    const float* B[2][4];
    for (int l = 0; l < 2; ++l) {
        for (int j = 0; j < 4; ++j) W[l][j] = (const float*)d_in[3 + l * 8 + j];
        for (int j = 0; j < 4; ++j) B[l][j] = (const float*)d_in[3 + l * 8 + 4 + j];
    }
    const float* Wc1 = (const float*)d_in[19];
    const float* bc1 = (const float*)d_in[20];
    const float* Wc2 = (const float*)d_in[21];
    const float* bc2 = (const float*)d_in[22];
    float* out = (float*)d_out;

    const int* src = ei;        // edge_index[0]
    const int* dst = ei + Ee;   // edge_index[1]

    char* p = (char*)d_ws;
    auto alloc = [&](size_t bytes) {
        void* r = (void*)p;
        p += (bytes + 255) & ~(size_t)255;
        return r;
    };
    char*     q  = (char*)alloc((size_t)Nn * 128);          // int8 (scale 16)
    char*     kv = (char*)alloc((size_t)Nn * 256);          // [k_int8|v_fp8]
    ushort_t* ss = (ushort_t*)alloc((size_t)Nn * 128 * 2);  // bf16
    ushort_t* hb = (ushort_t*)alloc((size_t)Nn * 128 * 2);  // bf16 layer-2 h
    ushort_t* Xh = (ushort_t*)alloc((size_t)Nn * 128 * 2);
    ushort_t* Xl = (ushort_t*)alloc((size_t)Nn * 128 * 2);
    ushort_t* Wfh = (ushort_t*)alloc((size_t)8 * 16384 * 2);
    ushort_t* Wfl = (ushort_t*)alloc((size_t)8 * 16384 * 2);
    char* zbase = p;  // region zeroed each launch
    int*   counts = (int*)alloc((size_t)Nn * CPAD * 4);     // 64B-padded counters
    int*   startg = (int*)alloc(Gg * 4);
    int*   endg   = (int*)alloc(Gg * 4);
    float* pooled = (float*)alloc(Gg * Dd * 4);
    size_t zbytes = (size_t)(p - zbase);
    int* offsets    = (int*)alloc((size_t)(Nn + 1) * 4);
    int* rank       = (int*)alloc((size_t)Ee * 4);
    int* blockSums  = (int*)alloc(256 * 4);
    int* sorted_src = (int*)alloc((size_t)Ee * 4);

    hipMemsetAsync(zbase, 0, zbytes, stream);

    constexpr int NB = (Nn + 255) / 256;  // 196 scan blocks

    // prep: hist(+rank) + bounds + convw + convx (independent, one launch)
    prep_kernel<<<EB8 + NBD + CWB + CXB, 256, 0, stream>>>(
        dst, counts, rank, batch, startg, endg,
        W[0][0], W[0][1], W[0][2], W[0][3], W[1][0], W[1][1], W[1][2], W[1][3],
        Wfh, Wfl, x, Xh, Xl);
    scan1_kernel<<<NB, 256, 0, stream>>>(counts, offsets, blockSums);
    scan2_kernel<<<1, 256, 0, stream>>>(blockSums, NB);
    // scan3 folded into consumers (offsets[i] + blockSums[i>>8])

    // layer-0 gemm fused with atomic-free scatter
    gemm0_scatter_kernel<<<G0B + EB4, 256, 0, stream>>>(
        Xh, Xl, Wfh, Wfl, B[0][0], B[0][1], B[0][2], B[0][3],
        q, kv, ss, src, dst, offsets, rank, blockSums, sorted_src);

    // layer-0 attn writes split-bf16 h straight into Xh/Xl (2 nodes/wave)
    attn_kernel<<<Nn / 8, 256, 0, stream>>>(q, kv, ss, offsets, blockSums,
                                            sorted_src, Xh, Xl, 1);
    // layer 1 (1D grid + XCD-group swizzle)
    gemm_mfma_kernel<<<NT * 4, 256, 0, stream>>>(Xh, Xl, Wfh, Wfl, 4,
                                                 B[1][0], B[1][1], B[1][2], B[1][3],
                                                 q, kv, ss);
    attn_kernel<<<Nn / 8, 256, 0, stream>>>(q, kv, ss, offsets, blockSums,
                                            sorted_src, hb, hb, 0);

    pool_kernel<<<(Nn + 255) / 256, 256, 0, stream>>>(hb, batch, pooled);
    mlp_kernel<<<Gg, 64, 0, stream>>>(pooled, startg, endg, Wc1, bc1, Wc2, bc2, out);
}